// Round 8
// baseline (170.989 us; speedup 1.0000x reference)
//
#include <hip/hip_runtime.h>

typedef float f32x4 __attribute__((ext_vector_type(4)));
typedef __bf16 bf16x8 __attribute__((ext_vector_type(8)));
typedef unsigned short us8 __attribute__((ext_vector_type(8)));
typedef unsigned short us4 __attribute__((ext_vector_type(4)));

#define QSCALE 11.541560327111707f   // 8 * log2(e) -> softmax in exp2 domain
#define NEG_INF (-__builtin_inff())

__device__ __forceinline__ float fexp2(float x) {
    return __builtin_amdgcn_exp2f(x);
}
__device__ __forceinline__ unsigned short f2bf(float x) {   // round-nearest
    unsigned u = __builtin_bit_cast(unsigned, x);
    u += 0x7fffu + ((u >> 16) & 1u);
    return (unsigned short)(u >> 16);
}
__device__ __forceinline__ float bf2f(unsigned short h) {
    unsigned u = ((unsigned)h) << 16;
    return __builtin_bit_cast(float, u);
}
__device__ __forceinline__ unsigned short bftrunc(float x) { // truncate
    return (unsigned short)(__builtin_bit_cast(unsigned, x) >> 16);
}
__device__ __forceinline__ f32x4 mfma16(us8 a, us8 b, f32x4 c) {
    return __builtin_amdgcn_mfma_f32_16x16x32_bf16(
        __builtin_bit_cast(bf16x8, a), __builtin_bit_cast(bf16x8, b), c, 0, 0, 0);
}
__device__ __forceinline__ void glds16(const unsigned short* g, unsigned short* l) {
    __builtin_amdgcn_global_load_lds(
        (const __attribute__((address_space(1))) unsigned int*)g,
        (__attribute__((address_space(3))) unsigned int*)l, 16, 0, 0);
}
// split 8 fp32 (2x float4) into hi/lo bf16 (trunc split)
__device__ __forceinline__ void splitx(float4 a, float4 b, us8& h, us8& lo) {
    float xf[8] = {a.x, a.y, a.z, a.w, b.x, b.y, b.z, b.w};
#pragma unroll
    for (int e = 0; e < 8; ++e) {
        unsigned u = __builtin_bit_cast(unsigned, xf[e]);
        h[e] = (unsigned short)(u >> 16);
        lo[e] = bftrunc(xf[e] - __builtin_bit_cast(float, u & 0xffff0000u));
    }
}

// ---------------- Kernel 0: W transpose + split (RN split) ----------------
__global__ __launch_bounds__(256) void wprep_kernel(
    const float* __restrict__ Wq, const float* __restrict__ Wk,
    const float* __restrict__ Wv,
    unsigned short* __restrict__ Wthi, unsigned short* __restrict__ Wtlo)
{
    __shared__ __align__(16) float Ls[64][68];
    const int g = blockIdx.x >> 4;
    const int k0 = (blockIdx.x & 15) << 6;
    const float* W = (g == 0) ? Wq : (g == 1) ? Wk : Wv;
    const int t = threadIdx.x;
#pragma unroll
    for (int u = 0; u < 4; ++u) {
        int idx = t + (u << 8);
        int row = idx >> 4, c4 = (idx & 15) << 2;
        *(float4*)&Ls[row][c4] = *(const float4*)&W[(size_t)(k0 + row) * 64 + c4];
    }
    __syncthreads();
    const int h = t >> 2, kk0 = (t & 3) << 4;
    size_t base = (size_t)((g << 6) + h) * 1024 + k0 + kk0;
#pragma unroll
    for (int c = 0; c < 4; ++c) {
        us4 hv, lv;
#pragma unroll
        for (int i = 0; i < 4; ++i) {
            float x = Ls[kk0 + (c << 2) + i][h];
            unsigned short hh = f2bf(x);
            hv[i] = hh;
            lv[i] = f2bf(x - bf2f(hh));
        }
        *(us4*)&Wthi[base + (c << 2)] = hv;
        *(us4*)&Wtlo[base + (c << 2)] = lv;
    }
}

// ---------------- Kernel 1: fused QKV projection ----------------
// v9 = v8 (counted-vmcnt, triple-buffer, raw s_barrier) + 2x2 WAVE DECOMP:
// wave (wq,wc) owns 32 rows x 48 cols -> still 36 MFMA/wave/iter but only
// 12 ds_read_b128 (12 KB) instead of 24 -> LDS pipe traffic HALVED
// (192->96 KB/CU/iter, the largest modeled consumer at ~2300cy/iter).
// X: direct global, 2 rt x 4 float4; both col-waves read the same 16KB
// X-slice in the same phase -> second read is an L1 hit (HBM unchanged).
// Per iter issue = 6 glds + 8 X = 14 -> steady wait is vmcnt(14).
__global__ __launch_bounds__(256, 2) void qkv_kernel(
    const float* __restrict__ X,
    const unsigned short* __restrict__ Wthi,
    const unsigned short* __restrict__ Wtlo,
    unsigned short* __restrict__ Qhi, unsigned short* __restrict__ Qlo,
    unsigned short* __restrict__ Khi, unsigned short* __restrict__ Klo,
    unsigned short* __restrict__ Vthi)
{
    __shared__ __align__(16) unsigned short sm[38144];  // 74.5 KB
    unsigned short* Wh = sm;              // 3 buf x 12288 us ([hi 6144 | lo 6144])
    unsigned short* Vx = sm + 36864;      // 4x16x20 transpose scratch

    const int t = threadIdx.x;
    const int w = t >> 6, l = t & 63, lm = l & 15, lg = (l >> 4) & 3;
    const int wq = w >> 1, wc = w & 1;
    const int m0 = blockIdx.x << 6;
    const int y  = blockIdx.y;

    // --- W glds staging (unchanged from v8): per wave 3 hi + 3 lo chunks ---
    size_t woff[3];
    int gdst[3];
#pragma unroll
    for (int i = 0; i < 3; ++i) {
        int g = w * 3 + i;                      // 0..11
        int n = (g << 3) + (l >> 3);            // W row 0..95
        int cg = (l & 7) ^ ((l >> 3) & 7);      // swizzled source chunk
        woff[i] = (size_t)(y * 96 + n) * 1024 + (cg << 3);
        gdst[i] = g << 9;                       // g*512 us
    }
    // --- X direct per-lane pointers: wave owns rows wq*32 .. +32 (2 rt) ---
    const float* xp0 = X + (size_t)(m0 + (wq << 5) + lm) * 1024 + (lg << 3);
    const float* xp1 = xp0 + (size_t)16 * 1024;

    // --- W fragment LDS offsets for this wave's col half (3 ct) ---
    int boff[3][2];
#pragma unroll
    for (int ct = 0; ct < 3; ++ct)
#pragma unroll
        for (int kc = 0; kc < 2; ++kc) {
            int n = wc * 48 + (ct << 4) + lm;
            boff[ct][kc] = (n << 6) + ((((kc << 2) + lg) ^ (lm & 7)) << 3);
        }

    f32x4 acc[2][3];
#pragma unroll
    for (int i = 0; i < 2; ++i)
#pragma unroll
        for (int j = 0; j < 3; ++j) acc[i][j] = (f32x4){0.f, 0.f, 0.f, 0.f};

    float4 xA[2][4], xB[2][4];      // X(k): even k in A, odd k in B
    us8 ah[2][2], al[2][2];         // [rt][kc]

    // ---- prologue: X0, G0, X1, G1 issued (28 in flight); drain oldest 14 ----
    xA[0][0] = *(const float4*)(xp0);      xA[0][1] = *(const float4*)(xp0 + 4);
    xA[0][2] = *(const float4*)(xp0 + 32); xA[0][3] = *(const float4*)(xp0 + 36);
    xA[1][0] = *(const float4*)(xp1);      xA[1][1] = *(const float4*)(xp1 + 4);
    xA[1][2] = *(const float4*)(xp1 + 32); xA[1][3] = *(const float4*)(xp1 + 36);
#pragma unroll
    for (int i = 0; i < 3; ++i) glds16(Wthi + woff[i], Wh + gdst[i]);
#pragma unroll
    for (int i = 0; i < 3; ++i) glds16(Wtlo + woff[i], Wh + 6144 + gdst[i]);
    xB[0][0] = *(const float4*)(xp0 + 64); xB[0][1] = *(const float4*)(xp0 + 68);
    xB[0][2] = *(const float4*)(xp0 + 96); xB[0][3] = *(const float4*)(xp0 + 100);
    xB[1][0] = *(const float4*)(xp1 + 64); xB[1][1] = *(const float4*)(xp1 + 68);
    xB[1][2] = *(const float4*)(xp1 + 96); xB[1][3] = *(const float4*)(xp1 + 100);
#pragma unroll
    for (int i = 0; i < 3; ++i) glds16(Wthi + woff[i] + 64, Wh + 12288 + gdst[i]);
#pragma unroll
    for (int i = 0; i < 3; ++i) glds16(Wtlo + woff[i] + 64, Wh + 12288 + 6144 + gdst[i]);
    asm volatile("s_waitcnt vmcnt(14)" ::: "memory");    // X0+G0 done
    __builtin_amdgcn_sched_barrier(0);
#pragma unroll
    for (int rt = 0; rt < 2; ++rt) {
        splitx(xA[rt][0], xA[rt][1], ah[rt][0], al[rt][0]);
        splitx(xA[rt][2], xA[rt][3], ah[rt][1], al[rt][1]);
    }
    __builtin_amdgcn_s_barrier();                        // buf0 visible

#pragma unroll
    for (int k = 0; k < 16; ++k) {
        const int wb = (k % 3) * 12288;
        // ---- issue phase: glds(k+2) + X(k+2), queue -> 28 ----
        if (k < 14) {
            const int nb = ((k + 2) % 3) * 12288;
            const size_t ko = (size_t)(k + 2) << 6;
#pragma unroll
            for (int i = 0; i < 3; ++i)
                glds16(Wthi + woff[i] + ko, Wh + nb + gdst[i]);
#pragma unroll
            for (int i = 0; i < 3; ++i)
                glds16(Wtlo + woff[i] + ko, Wh + nb + 6144 + gdst[i]);
            const int kg = (k + 2) << 6;
            if ((k & 1) == 0) {
                xA[0][0] = *(const float4*)(xp0 + kg);      xA[0][1] = *(const float4*)(xp0 + kg + 4);
                xA[0][2] = *(const float4*)(xp0 + kg + 32); xA[0][3] = *(const float4*)(xp0 + kg + 36);
                xA[1][0] = *(const float4*)(xp1 + kg);      xA[1][1] = *(const float4*)(xp1 + kg + 4);
                xA[1][2] = *(const float4*)(xp1 + kg + 32); xA[1][3] = *(const float4*)(xp1 + kg + 36);
            } else {
                xB[0][0] = *(const float4*)(xp0 + kg);      xB[0][1] = *(const float4*)(xp0 + kg + 4);
                xB[0][2] = *(const float4*)(xp0 + kg + 32); xB[0][3] = *(const float4*)(xp0 + kg + 36);
                xB[1][0] = *(const float4*)(xp1 + kg);      xB[1][1] = *(const float4*)(xp1 + kg + 4);
                xB[1][2] = *(const float4*)(xp1 + kg + 32); xB[1][3] = *(const float4*)(xp1 + kg + 36);
            }
        }
        __builtin_amdgcn_sched_barrier(0);   // pin issue block above compute
        // ---- compute: 12 ds_read_b128 + 36 MFMA on buf[k%3] ----
        us8 bh[3][2], bl[3][2];
#pragma unroll
        for (int ct = 0; ct < 3; ++ct)
#pragma unroll
            for (int kc = 0; kc < 2; ++kc) {
                bh[ct][kc] = *(const us8*)&Wh[wb + boff[ct][kc]];
                bl[ct][kc] = *(const us8*)&Wh[wb + 6144 + boff[ct][kc]];
            }
#pragma unroll
        for (int kc = 0; kc < 2; ++kc)
#pragma unroll
            for (int rt = 0; rt < 2; ++rt)
#pragma unroll
                for (int ct = 0; ct < 3; ++ct) {
                    acc[rt][ct] = mfma16(ah[rt][kc], bh[ct][kc], acc[rt][ct]);
                    acc[rt][ct] = mfma16(al[rt][kc], bh[ct][kc], acc[rt][ct]);
                    acc[rt][ct] = mfma16(ah[rt][kc], bl[ct][kc], acc[rt][ct]);
                }
        // ---- counted drain: oldest 14 = glds(k+1)+X(k+1); 14 stay in flight
        if (k < 14)       asm volatile("s_waitcnt vmcnt(14)" ::: "memory");
        else if (k == 14) asm volatile("s_waitcnt vmcnt(0)" ::: "memory");
        __builtin_amdgcn_sched_barrier(0);
        if (k < 15) {
            if ((k & 1) == 0) {   // split X(k+1) (odd -> lives in B)
#pragma unroll
                for (int rt = 0; rt < 2; ++rt) {
                    splitx(xB[rt][0], xB[rt][1], ah[rt][0], al[rt][0]);
                    splitx(xB[rt][2], xB[rt][3], ah[rt][1], al[rt][1]);
                }
            } else {
#pragma unroll
                for (int rt = 0; rt < 2; ++rt) {
                    splitx(xA[rt][0], xA[rt][1], ah[rt][0], al[rt][0]);
                    splitx(xA[rt][2], xA[rt][3], ah[rt][1], al[rt][1]);
                }
            }
            __builtin_amdgcn_s_barrier();    // raw barrier: NO implicit drain
        }
    }

    // ---- epilogue (v0's proven 2x2 version): trunc-split stores; Q pre-scaled;
    //      V transposed via Vx ----
    const int tbr = m0 + (wq << 5);
#pragma unroll
    for (int rt = 0; rt < 2; ++rt) {
#pragma unroll
        for (int ct = 0; ct < 3; ++ct) {
            const int gc = y * 96 + wc * 48 + (ct << 4);
            if (gc < 128) {
                unsigned short* Dh = (gc < 64) ? Qhi : Khi;
                unsigned short* Dl = (gc < 64) ? Qlo : Klo;
                const float sc = (gc < 64) ? QSCALE : 1.0f;
                const int colb = (gc & 63) + lm;
#pragma unroll
                for (int r = 0; r < 4; ++r) {
                    int row = tbr + (rt << 4) + (lg << 2) + r;
                    float x = acc[rt][ct][r] * sc;
                    unsigned u = __builtin_bit_cast(unsigned, x);
                    size_t o = (size_t)row * 64 + colb;
                    Dh[o] = (unsigned short)(u >> 16);
                    Dl[o] = bftrunc(x - __builtin_bit_cast(float, u & 0xffff0000u));
                }
            } else {
                // V: 16x16 transpose via wave-local LDS
#pragma unroll
                for (int r = 0; r < 4; ++r)
                    Vx[w * 320 + lm * 20 + (lg << 2) + r] = bftrunc(acc[rt][ct][r]);
                __asm__ volatile("" ::: "memory");
                const int h0 = gc - 128;
                const int tb = tbr + (rt << 4);
                const int bb = tb >> 11;
                const int tl = (tb & 2047) + ((l & 3) << 2);
                const int hh2 = h0 + (l >> 2);
                us4 vv = *(const us4*)&Vx[w * 320 + (l >> 2) * 20 + ((l & 3) << 2)];
                *(us4*)&Vthi[(size_t)((bb << 6) + hh2) * 2048 + tl] = vv;
                __asm__ volatile("" ::: "memory");
            }
        }
    }
}

// ---------------- Kernel 2: causal flash attention ----------------
// 512 blocks = (b, 32-row q-tile, heavy-first). 4 waves = 4 key-parities,
// ZERO barriers in the K-loop (K/V frags direct from global, L2-resident).
// S^T layout: lane = q-row -> softmax reduce = 15 local ops + 2 shuffles.
// exp2 domain (Q pre-scaled by 8*log2e). 4-way merge at end.
__global__ __launch_bounds__(256, 2) void attn_kernel(
    const unsigned short* __restrict__ Qhi, const unsigned short* __restrict__ Qlo,
    const unsigned short* __restrict__ Khi, const unsigned short* __restrict__ Klo,
    const unsigned short* __restrict__ Vthi,
    float* __restrict__ O)
{
    __shared__ __align__(16) unsigned char smem[33792];
    unsigned short* PS = (unsigned short*)smem;     // [4][32][72] us (loop phase)
    float* FO = (float*)smem;                       // [4][32][64] f32 (merge phase)
    float* FM = (float*)(smem + 32768);             // [4][32]
    float* FL = FM + 128;

    const int t = threadIdx.x;
    const int w = t >> 6, l = t & 63, lm = l & 15, lg = (l >> 4) & 3;
    const int b = blockIdx.x & 7;
    const int qp = 63 - (blockIdx.x >> 3);          // heavy tiles first
    const int nk = (qp >> 1) + 1;                   // 64-key tiles needed
    const int q0 = qp << 5;
    const size_t brow = (size_t)b << 11;

    // Q fragments pinned (B-operand: lane=qrow, k=lg*8+j)
    us8 qh[2][2], ql[2][2];
#pragma unroll
    for (int nt = 0; nt < 2; ++nt)
#pragma unroll
        for (int kc = 0; kc < 2; ++kc) {
            size_t off = (brow + q0 + (nt << 4) + lm) * 64 + (kc << 5) + (lg << 3);
            qh[nt][kc] = *(const us8*)&Qhi[off];
            ql[nt][kc] = *(const us8*)&Qlo[off];
        }

    f32x4 o_acc[2][4];
#pragma unroll
    for (int nt = 0; nt < 2; ++nt)
#pragma unroll
        for (int ct = 0; ct < 4; ++ct) o_acc[nt][ct] = (f32x4){0.f, 0.f, 0.f, 0.f};
    float m_r[2] = {NEG_INF, NEG_INF}, l_r[2] = {0.f, 0.f};
    unsigned short* ps = PS + w * 2304;             // wave-local 32x72

    for (int j = w; j < nk; j += 4) {
        const int kk0 = j << 6;
        us8 kh[4][2], klo[4][2], vh[4][2];
#pragma unroll
        for (int mt = 0; mt < 4; ++mt)
#pragma unroll
            for (int kc = 0; kc < 2; ++kc) {
                size_t off = (brow + kk0 + (mt << 4) + lm) * 64 + (kc << 5) + (lg << 3);
                kh[mt][kc] = *(const us8*)&Khi[off];
                klo[mt][kc] = *(const us8*)&Klo[off];
            }
#pragma unroll
        for (int ct = 0; ct < 4; ++ct)
#pragma unroll
            for (int kc = 0; kc < 2; ++kc) {
                size_t off = ((size_t)(b << 6) + (ct << 4) + lm) * 2048
                           + kk0 + (kc << 5) + (lg << 3);
                vh[ct][kc] = *(const us8*)&Vthi[off];
            }
        // S^T = K Q^T (split-bf16)
        f32x4 s[4][2];
#pragma unroll
        for (int mt = 0; mt < 4; ++mt)
#pragma unroll
            for (int nt = 0; nt < 2; ++nt) s[mt][nt] = (f32x4){0.f, 0.f, 0.f, 0.f};
#pragma unroll
        for (int kc = 0; kc < 2; ++kc)
#pragma unroll
            for (int mt = 0; mt < 4; ++mt)
#pragma unroll
                for (int nt = 0; nt < 2; ++nt) {
                    s[mt][nt] = mfma16(kh[mt][kc], qh[nt][kc], s[mt][nt]);
                    s[mt][nt] = mfma16(klo[mt][kc], qh[nt][kc], s[mt][nt]);
                    s[mt][nt] = mfma16(kh[mt][kc], ql[nt][kc], s[mt][nt]);
                }
        // online softmax (exp2 domain), lane owns row q0+nt*16+lm, 16 keys
        float alz[2];
#pragma unroll
        for (int nt = 0; nt < 2; ++nt) {
            const int qr = q0 + (nt << 4) + lm;
            float sv[16];
            if ((kk0 + 63) <= (q0 + (nt << 4))) {
#pragma unroll
                for (int mt = 0; mt < 4; ++mt)
#pragma unroll
                    for (int r = 0; r < 4; ++r) sv[(mt << 2) + r] = s[mt][nt][r];
            } else {
#pragma unroll
                for (int mt = 0; mt < 4; ++mt)
#pragma unroll
                    for (int r = 0; r < 4; ++r) {
                        const int key = kk0 + (mt << 4) + (lg << 2) + r;
                        sv[(mt << 2) + r] = (key <= qr) ? s[mt][nt][r] : NEG_INF;
                    }
            }
            float t8[8];
#pragma unroll
            for (int i = 0; i < 8; ++i) t8[i] = fmaxf(sv[i], sv[i + 8]);
#pragma unroll
            for (int i = 0; i < 4; ++i) t8[i] = fmaxf(t8[i], t8[i + 4]);
            float mx = fmaxf(fmaxf(t8[0], t8[1]), fmaxf(t8[2], t8[3]));
            mx = fmaxf(mx, __shfl_xor(mx, 16));
            mx = fmaxf(mx, __shfl_xor(mx, 32));
            const float mn = fmaxf(m_r[nt], mx);
            alz[nt] = fexp2(m_r[nt] - mn);
            m_r[nt] = mn;
            float p[16];
#pragma unroll
            for (int i = 0; i < 16; ++i) p[i] = fexp2(sv[i] - mn);
#pragma unroll
            for (int mt = 0; mt < 4; ++mt) {
                us4 pk;
#pragma unroll
                for (int r = 0; r < 4; ++r) pk[r] = bftrunc(p[(mt << 2) + r]);
                *(us4*)&ps[((nt << 4) + lm) * 72 + (mt << 4) + (lg << 2)] = pk;
            }
            float s8[8];
#pragma unroll
            for (int i = 0; i < 8; ++i) s8[i] = p[i] + p[i + 8];
#pragma unroll
            for (int i = 0; i < 4; ++i) s8[i] = s8[i] + s8[i + 4];
            float rs = (s8[0] + s8[1]) + (s8[2] + s8[3]);
            rs += __shfl_xor(rs, 16);
            rs += __shfl_xor(rs, 32);
            l_r[nt] = l_r[nt] * alz[nt] + rs;
        }
        __asm__ volatile("" ::: "memory");   // P write -> read, same wave
        // rescale O (alz lives at lane=row; fetch via shuffle)
#pragma unroll
        for (int nt = 0; nt < 2; ++nt)
#pragma unroll
            for (int r = 0; r < 4; ++r) {
                const float av = __shfl(alz[nt], (lg << 2) + r);
#pragma unroll
                for (int ct = 0; ct < 4; ++ct) o_acc[nt][ct][r] *= av;
            }
        // O += P V
#pragma unroll
        for (int nt = 0; nt < 2; ++nt)
#pragma unroll
            for (int kc = 0; kc < 2; ++kc) {
                us8 pa = *(const us8*)&ps[((nt << 4) + lm) * 72 + (kc << 5) + (lg << 3)];
#pragma unroll
                for (int ct = 0; ct < 4; ++ct)
                    o_acc[nt][ct] = mfma16(pa, vh[ct][kc], o_acc[nt][ct]);
            }
    }

    // ---- 4-way key-parity merge ----
    __syncthreads();                         // all PS use done before FO alias
#pragma unroll
    for (int nt = 0; nt < 2; ++nt)
#pragma unroll
        for (int ct = 0; ct < 4; ++ct)
#pragma unroll
            for (int r = 0; r < 4; ++r)
                FO[(w << 11) + (((nt << 4) + (lg << 2) + r) << 6) + (ct << 4) + lm]
                    = o_acc[nt][ct][r];
    if (l < 16) {
        FM[(w << 5) + lm] = m_r[0]; FM[(w << 5) + 16 + lm] = m_r[1];
        FL[(w << 5) + lm] = l_r[0]; FL[(w << 5) + 16 + lm] = l_r[1];
    }
    __syncthreads();
    const int jr = t >> 3;                   // row 0..31
    const int cg = (t & 7) << 3;             // col base
    float m0v = FM[jr], m1v = FM[32 + jr], m2v = FM[64 + jr], m3v = FM[96 + jr];
    float mm = fmaxf(fmaxf(m0v, m1v), fmaxf(m2v, m3v));
    float a0 = fexp2(m0v - mm), a1 = fexp2(m1v - mm);
    float a2 = fexp2(m2v - mm), a3 = fexp2(m3v - mm);
    float L = a0 * FL[jr] + a1 * FL[32 + jr] + a2 * FL[64 + jr] + a3 * FL[96 + jr];
    float inv = 1.0f / L;
    float ov[8];
#pragma unroll
    for (int c = 0; c < 8; ++c)
        ov[c] = a0 * FO[(jr << 6) + cg + c] + a1 * FO[2048 + (jr << 6) + cg + c]
              + a2 * FO[4096 + (jr << 6) + cg + c] + a3 * FO[6144 + (jr << 6) + cg + c];
    float4 o1 = {ov[0] * inv, ov[1] * inv, ov[2] * inv, ov[3] * inv};
    float4 o2 = {ov[4] * inv, ov[5] * inv, ov[6] * inv, ov[7] * inv};
    float* op = O + (brow + q0 + jr) * 64 + cg;
    *(float4*)op = o1;
    *(float4*)(op + 4) = o2;
}

extern "C" void kernel_launch(void* const* d_in, const int* in_sizes, int n_in,
                              void* d_out, int out_size, void* d_ws, size_t ws_size,
                              hipStream_t stream) {
    const float* X  = (const float*)d_in[0];
    const float* Wq = (const float*)d_in[1];
    const float* Wk = (const float*)d_in[2];
    const float* Wv = (const float*)d_in[3];
    unsigned short* ws = (unsigned short*)d_ws;
    const size_t SZ = (size_t)16384 * 64;
    unsigned short* Qhi  = ws;
    unsigned short* Qlo  = ws + SZ;
    unsigned short* Khi  = ws + 2 * SZ;
    unsigned short* Klo  = ws + 3 * SZ;
    unsigned short* Vthi = ws + 4 * SZ;
    unsigned short* Wthi = ws + 5 * SZ;
    unsigned short* Wtlo = Wthi + 192 * 1024;

    wprep_kernel<<<48, 256, 0, stream>>>(Wq, Wk, Wv, Wthi, Wtlo);
    qkv_kernel<<<dim3(256, 2), 256, 0, stream>>>(X, Wthi, Wtlo,
                                                 Qhi, Qlo, Khi, Klo, Vthi);
    attn_kernel<<<512, 256, 0, stream>>>(Qhi, Qlo, Khi, Klo, Vthi, (float*)d_out);
}

// Round 9
// 162.783 us; speedup vs baseline: 1.0504x; 1.0504x over previous
//
#include <hip/hip_runtime.h>

typedef float f32x4 __attribute__((ext_vector_type(4)));
typedef __bf16 bf16x8 __attribute__((ext_vector_type(8)));
typedef unsigned short us8 __attribute__((ext_vector_type(8)));
typedef unsigned short us4 __attribute__((ext_vector_type(4)));

#define QSCALE 11.541560327111707f   // 8 * log2(e) -> softmax in exp2 domain
#define NEG_INF (-__builtin_inff())

__device__ __forceinline__ float fexp2(float x) {
    return __builtin_amdgcn_exp2f(x);
}
__device__ __forceinline__ unsigned short f2bf(float x) {   // round-nearest
    unsigned u = __builtin_bit_cast(unsigned, x);
    u += 0x7fffu + ((u >> 16) & 1u);
    return (unsigned short)(u >> 16);
}
__device__ __forceinline__ float bf2f(unsigned short h) {
    unsigned u = ((unsigned)h) << 16;
    return __builtin_bit_cast(float, u);
}
__device__ __forceinline__ unsigned short bftrunc(float x) { // truncate
    return (unsigned short)(__builtin_bit_cast(unsigned, x) >> 16);
}
__device__ __forceinline__ f32x4 mfma16(us8 a, us8 b, f32x4 c) {
    return __builtin_amdgcn_mfma_f32_16x16x32_bf16(
        __builtin_bit_cast(bf16x8, a), __builtin_bit_cast(bf16x8, b), c, 0, 0, 0);
}
__device__ __forceinline__ void glds16(const unsigned short* g, unsigned short* l) {
    __builtin_amdgcn_global_load_lds(
        (const __attribute__((address_space(1))) unsigned int*)g,
        (__attribute__((address_space(3))) unsigned int*)l, 16, 0, 0);
}
// split 8 fp32 (2x float4) into hi/lo bf16 (trunc split)
__device__ __forceinline__ void splitx(float4 a, float4 b, us8& h, us8& lo) {
    float xf[8] = {a.x, a.y, a.z, a.w, b.x, b.y, b.z, b.w};
#pragma unroll
    for (int e = 0; e < 8; ++e) {
        unsigned u = __builtin_bit_cast(unsigned, xf[e]);
        h[e] = (unsigned short)(u >> 16);
        lo[e] = bftrunc(xf[e] - __builtin_bit_cast(float, u & 0xffff0000u));
    }
}

// ---------------- Kernel 0: W transpose + split (RN split) ----------------
__global__ __launch_bounds__(256) void wprep_kernel(
    const float* __restrict__ Wq, const float* __restrict__ Wk,
    const float* __restrict__ Wv,
    unsigned short* __restrict__ Wthi, unsigned short* __restrict__ Wtlo)
{
    __shared__ __align__(16) float Ls[64][68];
    const int g = blockIdx.x >> 4;
    const int k0 = (blockIdx.x & 15) << 6;
    const float* W = (g == 0) ? Wq : (g == 1) ? Wk : Wv;
    const int t = threadIdx.x;
#pragma unroll
    for (int u = 0; u < 4; ++u) {
        int idx = t + (u << 8);
        int row = idx >> 4, c4 = (idx & 15) << 2;
        *(float4*)&Ls[row][c4] = *(const float4*)&W[(size_t)(k0 + row) * 64 + c4];
    }
    __syncthreads();
    const int h = t >> 2, kk0 = (t & 3) << 4;
    size_t base = (size_t)((g << 6) + h) * 1024 + k0 + kk0;
#pragma unroll
    for (int c = 0; c < 4; ++c) {
        us4 hv, lv;
#pragma unroll
        for (int i = 0; i < 4; ++i) {
            float x = Ls[kk0 + (c << 2) + i][h];
            unsigned short hh = f2bf(x);
            hv[i] = hh;
            lv[i] = f2bf(x - bf2f(hh));
        }
        *(us4*)&Wthi[base + (c << 2)] = hv;
        *(us4*)&Wtlo[base + (c << 2)] = lv;
    }
}

// ---------------- Kernel 1: fused QKV projection ----------------
// v10 = v8 (BEST: counted-vmcnt, triple-buffer, raw s_barrier, 43.3us)
// + same-y CU pairing: co-resident blocks (i, i+256) now share y, so their
// per-iter 24KB W glds streams hit the same L2/L1 lines instead of being
// disjoint. Decode: y=(i>>1)&1, r=(i&1)|((i>>2)<<1) — bijective, and
// bit1 of (i+256) is unchanged -> same y for the pair.
__global__ __launch_bounds__(256, 2) void qkv_kernel(
    const float* __restrict__ X,
    const unsigned short* __restrict__ Wthi,
    const unsigned short* __restrict__ Wtlo,
    unsigned short* __restrict__ Qhi, unsigned short* __restrict__ Qlo,
    unsigned short* __restrict__ Khi, unsigned short* __restrict__ Klo,
    unsigned short* __restrict__ Vthi)
{
    __shared__ __align__(16) unsigned short sm[38144];  // 74.5 KB
    unsigned short* Wh = sm;              // 3 buf x 12288 us ([hi 6144 | lo 6144])
    unsigned short* Vx = sm + 36864;      // 4x16x20 transpose scratch

    const int t = threadIdx.x;
    const int w = t >> 6, l = t & 63, lm = l & 15, lg = (l >> 4) & 3;
    const int bi = blockIdx.x;
    const int y  = (bi >> 1) & 1;
    const int m0 = (((bi >> 2) << 1) | (bi & 1)) << 6;

    // --- W glds staging: per wave 3 hi + 3 lo chunks (8 rows each, 1KB) ---
    size_t woff[3];
    int gdst[3];
#pragma unroll
    for (int i = 0; i < 3; ++i) {
        int g = w * 3 + i;                      // 0..11
        int n = (g << 3) + (l >> 3);            // W row 0..95
        int cg = (l & 7) ^ ((l >> 3) & 7);      // swizzled source chunk
        woff[i] = (size_t)(y * 96 + n) * 1024 + (cg << 3);
        gdst[i] = g << 9;                       // g*512 us
    }
    // --- X direct per-lane fragment pointer (wave owns rows w*16..w*16+16) ---
    const float* xptr = X + (size_t)(m0 + (w << 4) + lm) * 1024 + (lg << 3);

    // --- W fragment LDS offsets (swizzle: slot = (kc*4+lg) ^ (lm&7)) ---
    int boff[6][2];
#pragma unroll
    for (int ct = 0; ct < 6; ++ct)
#pragma unroll
        for (int kc = 0; kc < 2; ++kc) {
            int n = (ct << 4) + lm;
            boff[ct][kc] = (n << 6) + ((((kc << 2) + lg) ^ (lm & 7)) << 3);
        }

    f32x4 acc[6];
#pragma unroll
    for (int j = 0; j < 6; ++j) acc[j] = (f32x4){0.f, 0.f, 0.f, 0.f};

    float4 xA0, xA1, xA2, xA3, xB0, xB1, xB2, xB3;   // X(j) in (j&1)?B:A
    us8 ah[2], al[2];

    // ---- prologue: X0, G0, X1, G1 issued (20 in flight); drain oldest 10 ----
    xA0 = *(const float4*)(xptr);      xA1 = *(const float4*)(xptr + 4);
    xA2 = *(const float4*)(xptr + 32); xA3 = *(const float4*)(xptr + 36);
#pragma unroll
    for (int i = 0; i < 3; ++i) glds16(Wthi + woff[i], Wh + gdst[i]);
#pragma unroll
    for (int i = 0; i < 3; ++i) glds16(Wtlo + woff[i], Wh + 6144 + gdst[i]);
    xB0 = *(const float4*)(xptr + 64); xB1 = *(const float4*)(xptr + 68);
    xB2 = *(const float4*)(xptr + 96); xB3 = *(const float4*)(xptr + 100);
#pragma unroll
    for (int i = 0; i < 3; ++i) glds16(Wthi + woff[i] + 64, Wh + 12288 + gdst[i]);
#pragma unroll
    for (int i = 0; i < 3; ++i) glds16(Wtlo + woff[i] + 64, Wh + 12288 + 6144 + gdst[i]);
    asm volatile("s_waitcnt vmcnt(10)" ::: "memory");    // X0+G0 done
    __builtin_amdgcn_sched_barrier(0);
    splitx(xA0, xA1, ah[0], al[0]);
    splitx(xA2, xA3, ah[1], al[1]);
    __builtin_amdgcn_s_barrier();                        // buf0 visible

#pragma unroll
    for (int k = 0; k < 16; ++k) {
        const int wb = (k % 3) * 12288;
        // ---- issue phase: glds(k+2) + X(k+2), queue -> 20 ----
        if (k < 14) {
            const int nb = ((k + 2) % 3) * 12288;
            const size_t ko = (size_t)(k + 2) << 6;
#pragma unroll
            for (int i = 0; i < 3; ++i)
                glds16(Wthi + woff[i] + ko, Wh + nb + gdst[i]);
#pragma unroll
            for (int i = 0; i < 3; ++i)
                glds16(Wtlo + woff[i] + ko, Wh + nb + 6144 + gdst[i]);
            const int kg = (k + 2) << 6;
            if ((k & 1) == 0) {
                xA0 = *(const float4*)(xptr + kg);      xA1 = *(const float4*)(xptr + kg + 4);
                xA2 = *(const float4*)(xptr + kg + 32); xA3 = *(const float4*)(xptr + kg + 36);
            } else {
                xB0 = *(const float4*)(xptr + kg);      xB1 = *(const float4*)(xptr + kg + 4);
                xB2 = *(const float4*)(xptr + kg + 32); xB3 = *(const float4*)(xptr + kg + 36);
            }
        }
        __builtin_amdgcn_sched_barrier(0);   // pin issue block above compute
        // ---- compute: 24 ds_read_b128 + 36 MFMA on buf[k%3] ----
        us8 bh[6][2], bl[6][2];
#pragma unroll
        for (int ct = 0; ct < 6; ++ct)
#pragma unroll
            for (int kc = 0; kc < 2; ++kc) {
                bh[ct][kc] = *(const us8*)&Wh[wb + boff[ct][kc]];
                bl[ct][kc] = *(const us8*)&Wh[wb + 6144 + boff[ct][kc]];
            }
#pragma unroll
        for (int kc = 0; kc < 2; ++kc)
#pragma unroll
            for (int ct = 0; ct < 6; ++ct) {
                acc[ct] = mfma16(ah[kc], bh[ct][kc], acc[ct]);
                acc[ct] = mfma16(al[kc], bh[ct][kc], acc[ct]);
                acc[ct] = mfma16(ah[kc], bl[ct][kc], acc[ct]);
            }
        // ---- counted drain: oldest 10 = glds(k+1)+X(k+1); 10 stay in flight
        if (k < 14)       asm volatile("s_waitcnt vmcnt(10)" ::: "memory");
        else if (k == 14) asm volatile("s_waitcnt vmcnt(0)" ::: "memory");
        __builtin_amdgcn_sched_barrier(0);
        if (k < 15) {
            if ((k & 1) == 0) {   // split X(k+1) (odd -> lives in B)
                splitx(xB0, xB1, ah[0], al[0]);
                splitx(xB2, xB3, ah[1], al[1]);
            } else {
                splitx(xA0, xA1, ah[0], al[0]);
                splitx(xA2, xA3, ah[1], al[1]);
            }
            __builtin_amdgcn_s_barrier();    // raw barrier: NO implicit drain
        }
    }

    // ---- epilogue: trunc-split stores; Q pre-scaled; V transposed via Vx ----
    const int tbr = m0 + (w << 4);
#pragma unroll
    for (int ct = 0; ct < 6; ++ct) {
        const int gc = y * 96 + (ct << 4);
        if (gc < 128) {
            unsigned short* Dh = (gc < 64) ? Qhi : Khi;
            unsigned short* Dl = (gc < 64) ? Qlo : Klo;
            const float sc = (gc < 64) ? QSCALE : 1.0f;
            const int colb = (gc & 63) + lm;
#pragma unroll
            for (int r = 0; r < 4; ++r) {
                int row = tbr + (lg << 2) + r;
                float x = acc[ct][r] * sc;
                unsigned u = __builtin_bit_cast(unsigned, x);
                size_t o = (size_t)row * 64 + colb;
                Dh[o] = (unsigned short)(u >> 16);
                Dl[o] = bftrunc(x - __builtin_bit_cast(float, u & 0xffff0000u));
            }
        } else {
            // V: 16x16 transpose via wave-local LDS scratch
#pragma unroll
            for (int r = 0; r < 4; ++r)
                Vx[w * 320 + lm * 20 + (lg << 2) + r] = bftrunc(acc[ct][r]);
            __asm__ volatile("" ::: "memory");
            const int h0 = gc - 128;
            const int bb = tbr >> 11;
            const int tl = (tbr & 2047) + ((l & 3) << 2);
            const int hh2 = h0 + (l >> 2);
            us4 vv = *(const us4*)&Vx[w * 320 + (l >> 2) * 20 + ((l & 3) << 2)];
            *(us4*)&Vthi[(size_t)((bb << 6) + hh2) * 2048 + tl] = vv;
            __asm__ volatile("" ::: "memory");
        }
    }
}

// ---------------- Kernel 2: causal flash attention ----------------
// 512 blocks = (b, 32-row q-tile, heavy-first). 4 waves = 4 key-parities,
// ZERO barriers in the K-loop (K/V frags direct from global, L2-resident;
// b == blockIdx%8 == XCD -> same-b blocks share an XCD's L2 for K/V).
// v10: T5 s_setprio(1) around the QK and PV MFMA clusters — waves here are
// phase-independent (no barriers), the catalog's positive setprio regime.
__global__ __launch_bounds__(256, 2) void attn_kernel(
    const unsigned short* __restrict__ Qhi, const unsigned short* __restrict__ Qlo,
    const unsigned short* __restrict__ Khi, const unsigned short* __restrict__ Klo,
    const unsigned short* __restrict__ Vthi,
    float* __restrict__ O)
{
    __shared__ __align__(16) unsigned char smem[33792];
    unsigned short* PS = (unsigned short*)smem;     // [4][32][72] us (loop phase)
    float* FO = (float*)smem;                       // [4][32][64] f32 (merge phase)
    float* FM = (float*)(smem + 32768);             // [4][32]
    float* FL = FM + 128;

    const int t = threadIdx.x;
    const int w = t >> 6, l = t & 63, lm = l & 15, lg = (l >> 4) & 3;
    const int b = blockIdx.x & 7;
    const int qp = 63 - (blockIdx.x >> 3);          // heavy tiles first
    const int nk = (qp >> 1) + 1;                   // 64-key tiles needed
    const int q0 = qp << 5;
    const size_t brow = (size_t)b << 11;

    // Q fragments pinned (B-operand: lane=qrow, k=lg*8+j)
    us8 qh[2][2], ql[2][2];
#pragma unroll
    for (int nt = 0; nt < 2; ++nt)
#pragma unroll
        for (int kc = 0; kc < 2; ++kc) {
            size_t off = (brow + q0 + (nt << 4) + lm) * 64 + (kc << 5) + (lg << 3);
            qh[nt][kc] = *(const us8*)&Qhi[off];
            ql[nt][kc] = *(const us8*)&Qlo[off];
        }

    f32x4 o_acc[2][4];
#pragma unroll
    for (int nt = 0; nt < 2; ++nt)
#pragma unroll
        for (int ct = 0; ct < 4; ++ct) o_acc[nt][ct] = (f32x4){0.f, 0.f, 0.f, 0.f};
    float m_r[2] = {NEG_INF, NEG_INF}, l_r[2] = {0.f, 0.f};
    unsigned short* ps = PS + w * 2304;             // wave-local 32x72

    for (int j = w; j < nk; j += 4) {
        const int kk0 = j << 6;
        us8 kh[4][2], klo[4][2], vh[4][2];
#pragma unroll
        for (int mt = 0; mt < 4; ++mt)
#pragma unroll
            for (int kc = 0; kc < 2; ++kc) {
                size_t off = (brow + kk0 + (mt << 4) + lm) * 64 + (kc << 5) + (lg << 3);
                kh[mt][kc] = *(const us8*)&Khi[off];
                klo[mt][kc] = *(const us8*)&Klo[off];
            }
#pragma unroll
        for (int ct = 0; ct < 4; ++ct)
#pragma unroll
            for (int kc = 0; kc < 2; ++kc) {
                size_t off = ((size_t)(b << 6) + (ct << 4) + lm) * 2048
                           + kk0 + (kc << 5) + (lg << 3);
                vh[ct][kc] = *(const us8*)&Vthi[off];
            }
        // S^T = K Q^T (split-bf16)
        f32x4 s[4][2];
#pragma unroll
        for (int mt = 0; mt < 4; ++mt)
#pragma unroll
            for (int nt = 0; nt < 2; ++nt) s[mt][nt] = (f32x4){0.f, 0.f, 0.f, 0.f};
        __builtin_amdgcn_s_setprio(1);
#pragma unroll
        for (int kc = 0; kc < 2; ++kc)
#pragma unroll
            for (int mt = 0; mt < 4; ++mt)
#pragma unroll
                for (int nt = 0; nt < 2; ++nt) {
                    s[mt][nt] = mfma16(kh[mt][kc], qh[nt][kc], s[mt][nt]);
                    s[mt][nt] = mfma16(klo[mt][kc], qh[nt][kc], s[mt][nt]);
                    s[mt][nt] = mfma16(kh[mt][kc], ql[nt][kc], s[mt][nt]);
                }
        __builtin_amdgcn_s_setprio(0);
        // online softmax (exp2 domain), lane owns row q0+nt*16+lm, 16 keys
        float alz[2];
#pragma unroll
        for (int nt = 0; nt < 2; ++nt) {
            const int qr = q0 + (nt << 4) + lm;
            float sv[16];
            if ((kk0 + 63) <= (q0 + (nt << 4))) {
#pragma unroll
                for (int mt = 0; mt < 4; ++mt)
#pragma unroll
                    for (int r = 0; r < 4; ++r) sv[(mt << 2) + r] = s[mt][nt][r];
            } else {
#pragma unroll
                for (int mt = 0; mt < 4; ++mt)
#pragma unroll
                    for (int r = 0; r < 4; ++r) {
                        const int key = kk0 + (mt << 4) + (lg << 2) + r;
                        sv[(mt << 2) + r] = (key <= qr) ? s[mt][nt][r] : NEG_INF;
                    }
            }
            float t8[8];
#pragma unroll
            for (int i = 0; i < 8; ++i) t8[i] = fmaxf(sv[i], sv[i + 8]);
#pragma unroll
            for (int i = 0; i < 4; ++i) t8[i] = fmaxf(t8[i], t8[i + 4]);
            float mx = fmaxf(fmaxf(t8[0], t8[1]), fmaxf(t8[2], t8[3]));
            mx = fmaxf(mx, __shfl_xor(mx, 16));
            mx = fmaxf(mx, __shfl_xor(mx, 32));
            const float mn = fmaxf(m_r[nt], mx);
            alz[nt] = fexp2(m_r[nt] - mn);
            m_r[nt] = mn;
            float p[16];
#pragma unroll
            for (int i = 0; i < 16; ++i) p[i] = fexp2(sv[i] - mn);
#pragma unroll
            for (int mt = 0; mt < 4; ++mt) {
                us4 pk;
#pragma unroll
                for (int r = 0; r < 4; ++r) pk[r] = bftrunc(p[(mt << 2) + r]);
                *(us4*)&ps[((nt << 4) + lm) * 72 + (mt << 4) + (lg << 2)] = pk;
            }
            float s8[8];
#pragma unroll
            for (int i = 0; i < 8; ++i) s8[i] = p[i] + p[i + 8];
#pragma unroll
            for (int i = 0; i < 4; ++i) s8[i] = s8[i] + s8[i + 4];
            float rs = (s8[0] + s8[1]) + (s8[2] + s8[3]);
            rs += __shfl_xor(rs, 16);
            rs += __shfl_xor(rs, 32);
            l_r[nt] = l_r[nt] * alz[nt] + rs;
        }
        __asm__ volatile("" ::: "memory");   // P write -> read, same wave
        // rescale O (alz lives at lane=row; fetch via shuffle)
#pragma unroll
        for (int nt = 0; nt < 2; ++nt)
#pragma unroll
            for (int r = 0; r < 4; ++r) {
                const float av = __shfl(alz[nt], (lg << 2) + r);
#pragma unroll
                for (int ct = 0; ct < 4; ++ct) o_acc[nt][ct][r] *= av;
            }
        // O += P V
        __builtin_amdgcn_s_setprio(1);
#pragma unroll
        for (int nt = 0; nt < 2; ++nt)
#pragma unroll
            for (int kc = 0; kc < 2; ++kc) {
                us8 pa = *(const us8*)&ps[((nt << 4) + lm) * 72 + (kc << 5) + (lg << 3)];
#pragma unroll
                for (int ct = 0; ct < 4; ++ct)
                    o_acc[nt][ct] = mfma16(pa, vh[ct][kc], o_acc[nt][ct]);
            }
        __builtin_amdgcn_s_setprio(0);
    }

    // ---- 4-way key-parity merge ----
    __syncthreads();                         // all PS use done before FO alias
#pragma unroll
    for (int nt = 0; nt < 2; ++nt)
#pragma unroll
        for (int ct = 0; ct < 4; ++ct)
#pragma unroll
            for (int r = 0; r < 4; ++r)
                FO[(w << 11) + (((nt << 4) + (lg << 2) + r) << 6) + (ct << 4) + lm]
                    = o_acc[nt][ct][r];
    if (l < 16) {
        FM[(w << 5) + lm] = m_r[0]; FM[(w << 5) + 16 + lm] = m_r[1];
        FL[(w << 5) + lm] = l_r[0]; FL[(w << 5) + 16 + lm] = l_r[1];
    }
    __syncthreads();
    const int jr = t >> 3;                   // row 0..31
    const int cg = (t & 7) << 3;             // col base
    float m0v = FM[jr], m1v = FM[32 + jr], m2v = FM[64 + jr], m3v = FM[96 + jr];
    float mm = fmaxf(fmaxf(m0v, m1v), fmaxf(m2v, m3v));
    float a0 = fexp2(m0v - mm), a1 = fexp2(m1v - mm);
    float a2 = fexp2(m2v - mm), a3 = fexp2(m3v - mm);
    float L = a0 * FL[jr] + a1 * FL[32 + jr] + a2 * FL[64 + jr] + a3 * FL[96 + jr];
    float inv = 1.0f / L;
    float ov[8];
#pragma unroll
    for (int c = 0; c < 8; ++c)
        ov[c] = a0 * FO[(jr << 6) + cg + c] + a1 * FO[2048 + (jr << 6) + cg + c]
              + a2 * FO[4096 + (jr << 6) + cg + c] + a3 * FO[6144 + (jr << 6) + cg + c];
    float4 o1 = {ov[0] * inv, ov[1] * inv, ov[2] * inv, ov[3] * inv};
    float4 o2 = {ov[4] * inv, ov[5] * inv, ov[6] * inv, ov[7] * inv};
    float* op = O + (brow + q0 + jr) * 64 + cg;
    *(float4*)op = o1;
    *(float4*)(op + 4) = o2;
}

extern "C" void kernel_launch(void* const* d_in, const int* in_sizes, int n_in,
                              void* d_out, int out_size, void* d_ws, size_t ws_size,
                              hipStream_t stream) {
    const float* X  = (const float*)d_in[0];
    const float* Wq = (const float*)d_in[1];
    const float* Wk = (const float*)d_in[2];
    const float* Wv = (const float*)d_in[3];
    unsigned short* ws = (unsigned short*)d_ws;
    const size_t SZ = (size_t)16384 * 64;
    unsigned short* Qhi  = ws;
    unsigned short* Qlo  = ws + SZ;
    unsigned short* Khi  = ws + 2 * SZ;
    unsigned short* Klo  = ws + 3 * SZ;
    unsigned short* Vthi = ws + 4 * SZ;
    unsigned short* Wthi = ws + 5 * SZ;
    unsigned short* Wtlo = Wthi + 192 * 1024;

    wprep_kernel<<<48, 256, 0, stream>>>(Wq, Wk, Wv, Wthi, Wtlo);
    qkv_kernel<<<512, 256, 0, stream>>>(X, Wthi, Wtlo,
                                        Qhi, Qlo, Khi, Klo, Vthi);
    attn_kernel<<<512, 256, 0, stream>>>(Qhi, Qlo, Khi, Klo, Vthi, (float*)d_out);
}

// Round 10
// 156.699 us; speedup vs baseline: 1.0912x; 1.0388x over previous
//
#include <hip/hip_runtime.h>

typedef float f32x4 __attribute__((ext_vector_type(4)));
typedef __bf16 bf16x8 __attribute__((ext_vector_type(8)));
typedef unsigned short us8 __attribute__((ext_vector_type(8)));
typedef unsigned short us4 __attribute__((ext_vector_type(4)));

#define QSCALE 11.541560327111707f   // 8 * log2(e) -> softmax in exp2 domain
#define NEG_INF (-__builtin_inff())

__device__ __forceinline__ float fexp2(float x) {
    return __builtin_amdgcn_exp2f(x);
}
__device__ __forceinline__ unsigned short f2bf(float x) {   // round-nearest
    unsigned u = __builtin_bit_cast(unsigned, x);
    u += 0x7fffu + ((u >> 16) & 1u);
    return (unsigned short)(u >> 16);
}
__device__ __forceinline__ float bf2f(unsigned short h) {
    unsigned u = ((unsigned)h) << 16;
    return __builtin_bit_cast(float, u);
}
__device__ __forceinline__ unsigned short bftrunc(float x) { // truncate
    return (unsigned short)(__builtin_bit_cast(unsigned, x) >> 16);
}
__device__ __forceinline__ f32x4 mfma16(us8 a, us8 b, f32x4 c) {
    return __builtin_amdgcn_mfma_f32_16x16x32_bf16(
        __builtin_bit_cast(bf16x8, a), __builtin_bit_cast(bf16x8, b), c, 0, 0, 0);
}
__device__ __forceinline__ void glds16(const unsigned short* g, unsigned short* l) {
    __builtin_amdgcn_global_load_lds(
        (const __attribute__((address_space(1))) unsigned int*)g,
        (__attribute__((address_space(3))) unsigned int*)l, 16, 0, 0);
}
// split 8 fp32 (2x float4) into hi/lo bf16 (trunc split)
__device__ __forceinline__ void splitx(float4 a, float4 b, us8& h, us8& lo) {
    float xf[8] = {a.x, a.y, a.z, a.w, b.x, b.y, b.z, b.w};
#pragma unroll
    for (int e = 0; e < 8; ++e) {
        unsigned u = __builtin_bit_cast(unsigned, xf[e]);
        h[e] = (unsigned short)(u >> 16);
        lo[e] = bftrunc(xf[e] - __builtin_bit_cast(float, u & 0xffff0000u));
    }
}

// ---------------- Kernel 0: W transpose + split (RN split) ----------------
__global__ __launch_bounds__(256) void wprep_kernel(
    const float* __restrict__ Wq, const float* __restrict__ Wk,
    const float* __restrict__ Wv,
    unsigned short* __restrict__ Wthi, unsigned short* __restrict__ Wtlo)
{
    __shared__ __align__(16) float Ls[64][68];
    const int g = blockIdx.x >> 4;
    const int k0 = (blockIdx.x & 15) << 6;
    const float* W = (g == 0) ? Wq : (g == 1) ? Wk : Wv;
    const int t = threadIdx.x;
#pragma unroll
    for (int u = 0; u < 4; ++u) {
        int idx = t + (u << 8);
        int row = idx >> 4, c4 = (idx & 15) << 2;
        *(float4*)&Ls[row][c4] = *(const float4*)&W[(size_t)(k0 + row) * 64 + c4];
    }
    __syncthreads();
    const int h = t >> 2, kk0 = (t & 3) << 4;
    size_t base = (size_t)((g << 6) + h) * 1024 + k0 + kk0;
#pragma unroll
    for (int c = 0; c < 4; ++c) {
        us4 hv, lv;
#pragma unroll
        for (int i = 0; i < 4; ++i) {
            float x = Ls[kk0 + (c << 2) + i][h];
            unsigned short hh = f2bf(x);
            hv[i] = hh;
            lv[i] = f2bf(x - bf2f(hh));
        }
        *(us4*)&Wthi[base + (c << 2)] = hv;
        *(us4*)&Wtlo[base + (c << 2)] = lv;
    }
}

// ---------------- Kernel 1: fused QKV projection ----------------
// v11 = v8 pipeline (counted-vmcnt, triple-buffer, raw s_barrier) with
// FAT WAVES: 128-thread blocks, 2 waves x (32 UNIQUE rows x 96 cols).
// Halves CU LDS-read traffic per output (4 waves/CU x 24KB vs 8 x 24KB)
// with NO X duplication (r8's failure mode). Per wave per iter:
// 12 glds + 8 X float4 + 24 ds_read_b128 + 72 MFMA + 4 splitx.
// Queue: 20 issued/iter, 2 ahead -> steady wait vmcnt(20); never drains
// to 0 in the loop. Grid (256,2) = 512 blocks = 2 blocks/CU (149KB LDS).
__global__ __launch_bounds__(128, 1) void qkv_kernel(
    const float* __restrict__ X,
    const unsigned short* __restrict__ Wthi,
    const unsigned short* __restrict__ Wtlo,
    unsigned short* __restrict__ Qhi, unsigned short* __restrict__ Qlo,
    unsigned short* __restrict__ Khi, unsigned short* __restrict__ Klo,
    unsigned short* __restrict__ Vthi)
{
    __shared__ __align__(16) unsigned short sm[37504];  // 73.25 KB
    unsigned short* Wh = sm;              // 3 buf x 12288 us ([hi 6144 | lo 6144])
    unsigned short* Vx = sm + 36864;      // 2x320 transpose scratch

    const int t = threadIdx.x;            // 0..127
    const int w = t >> 6, l = t & 63, lm = l & 15, lg = (l >> 4) & 3;
    const int m0 = blockIdx.x << 6;
    const int y  = blockIdx.y;

    // --- W glds staging: wave w handles 12 chunks (w=0: hi, w=1: lo) ---
    const unsigned short* wsrc[12];
    int gdst[12];
#pragma unroll
    for (int i = 0; i < 12; ++i) {
        int g = w * 12 + i;                     // 0..23
        int half = (g >= 12) ? 1 : 0;
        int cc = g - 12 * half;                 // 0..11
        int n = (cc << 3) + (l >> 3);           // W row 0..95
        int cg = (l & 7) ^ ((l >> 3) & 7);      // swizzled source chunk
        wsrc[i] = (half ? Wtlo : Wthi) + (size_t)(y * 96 + n) * 1024 + (cg << 3);
        gdst[i] = half * 6144 + (cc << 9);
    }
    // --- X direct per-lane pointers: wave owns rows w*32 .. +32 (2 rt) ---
    const float* xp0 = X + (size_t)(m0 + (w << 5) + lm) * 1024 + (lg << 3);
    const float* xp1 = xp0 + (size_t)16 * 1024;

    // --- W fragment LDS offsets (swizzle: slot = (kc*4+lg) ^ (lm&7)) ---
    int boff[6][2];
#pragma unroll
    for (int ct = 0; ct < 6; ++ct)
#pragma unroll
        for (int kc = 0; kc < 2; ++kc) {
            int n = (ct << 4) + lm;
            boff[ct][kc] = (n << 6) + ((((kc << 2) + lg) ^ (lm & 7)) << 3);
        }

    f32x4 acc[2][6];
#pragma unroll
    for (int i = 0; i < 2; ++i)
#pragma unroll
        for (int j = 0; j < 6; ++j) acc[i][j] = (f32x4){0.f, 0.f, 0.f, 0.f};

    float4 xA[2][4], xB[2][4];      // X(k): even k in A, odd k in B
    us8 ah[2][2], al[2][2];         // [rt][kc]

    // ---- prologue: batch0 (X0+G0) and batch1 (X1+G1) issued; drain oldest 20
    xA[0][0] = *(const float4*)(xp0);      xA[0][1] = *(const float4*)(xp0 + 4);
    xA[0][2] = *(const float4*)(xp0 + 32); xA[0][3] = *(const float4*)(xp0 + 36);
    xA[1][0] = *(const float4*)(xp1);      xA[1][1] = *(const float4*)(xp1 + 4);
    xA[1][2] = *(const float4*)(xp1 + 32); xA[1][3] = *(const float4*)(xp1 + 36);
#pragma unroll
    for (int i = 0; i < 12; ++i) glds16(wsrc[i], Wh + gdst[i]);
    xB[0][0] = *(const float4*)(xp0 + 64); xB[0][1] = *(const float4*)(xp0 + 68);
    xB[0][2] = *(const float4*)(xp0 + 96); xB[0][3] = *(const float4*)(xp0 + 100);
    xB[1][0] = *(const float4*)(xp1 + 64); xB[1][1] = *(const float4*)(xp1 + 68);
    xB[1][2] = *(const float4*)(xp1 + 96); xB[1][3] = *(const float4*)(xp1 + 100);
#pragma unroll
    for (int i = 0; i < 12; ++i) glds16(wsrc[i] + 64, Wh + 12288 + gdst[i]);
    asm volatile("s_waitcnt vmcnt(20)" ::: "memory");    // X0+G0 done
    __builtin_amdgcn_sched_barrier(0);
#pragma unroll
    for (int rt = 0; rt < 2; ++rt) {
        splitx(xA[rt][0], xA[rt][1], ah[rt][0], al[rt][0]);
        splitx(xA[rt][2], xA[rt][3], ah[rt][1], al[rt][1]);
    }
    __builtin_amdgcn_s_barrier();                        // buf0 visible

#pragma unroll
    for (int k = 0; k < 16; ++k) {
        const int wb = (k % 3) * 12288;
        // ---- issue phase: glds(k+2) + X(k+2), queue -> 40 ----
        if (k < 14) {
            const int nb = ((k + 2) % 3) * 12288;
            const size_t ko = (size_t)(k + 2) << 6;
#pragma unroll
            for (int i = 0; i < 12; ++i)
                glds16(wsrc[i] + ko, Wh + nb + gdst[i]);
            const int kg = (k + 2) << 6;
            if ((k & 1) == 0) {
                xA[0][0] = *(const float4*)(xp0 + kg);      xA[0][1] = *(const float4*)(xp0 + kg + 4);
                xA[0][2] = *(const float4*)(xp0 + kg + 32); xA[0][3] = *(const float4*)(xp0 + kg + 36);
                xA[1][0] = *(const float4*)(xp1 + kg);      xA[1][1] = *(const float4*)(xp1 + kg + 4);
                xA[1][2] = *(const float4*)(xp1 + kg + 32); xA[1][3] = *(const float4*)(xp1 + kg + 36);
            } else {
                xB[0][0] = *(const float4*)(xp0 + kg);      xB[0][1] = *(const float4*)(xp0 + kg + 4);
                xB[0][2] = *(const float4*)(xp0 + kg + 32); xB[0][3] = *(const float4*)(xp0 + kg + 36);
                xB[1][0] = *(const float4*)(xp1 + kg);      xB[1][1] = *(const float4*)(xp1 + kg + 4);
                xB[1][2] = *(const float4*)(xp1 + kg + 32); xB[1][3] = *(const float4*)(xp1 + kg + 36);
            }
        }
        __builtin_amdgcn_sched_barrier(0);   // pin issue block above compute
        // ---- compute: 24 ds_read_b128 + 72 MFMA on buf[k%3] ----
        us8 bh[6][2], bl[6][2];
#pragma unroll
        for (int ct = 0; ct < 6; ++ct)
#pragma unroll
            for (int kc = 0; kc < 2; ++kc) {
                bh[ct][kc] = *(const us8*)&Wh[wb + boff[ct][kc]];
                bl[ct][kc] = *(const us8*)&Wh[wb + 6144 + boff[ct][kc]];
            }
#pragma unroll
        for (int kc = 0; kc < 2; ++kc)
#pragma unroll
            for (int rt = 0; rt < 2; ++rt)
#pragma unroll
                for (int ct = 0; ct < 6; ++ct) {
                    acc[rt][ct] = mfma16(ah[rt][kc], bh[ct][kc], acc[rt][ct]);
                    acc[rt][ct] = mfma16(al[rt][kc], bh[ct][kc], acc[rt][ct]);
                    acc[rt][ct] = mfma16(ah[rt][kc], bl[ct][kc], acc[rt][ct]);
                }
        // ---- counted drain: oldest 20 = glds(k+1)+X(k+1); 20 stay in flight
        if (k < 14)       asm volatile("s_waitcnt vmcnt(20)" ::: "memory");
        else if (k == 14) asm volatile("s_waitcnt vmcnt(0)" ::: "memory");
        __builtin_amdgcn_sched_barrier(0);
        if (k < 15) {
            if ((k & 1) == 0) {   // split X(k+1) (odd -> lives in B)
#pragma unroll
                for (int rt = 0; rt < 2; ++rt) {
                    splitx(xB[rt][0], xB[rt][1], ah[rt][0], al[rt][0]);
                    splitx(xB[rt][2], xB[rt][3], ah[rt][1], al[rt][1]);
                }
            } else {
#pragma unroll
                for (int rt = 0; rt < 2; ++rt) {
                    splitx(xA[rt][0], xA[rt][1], ah[rt][0], al[rt][0]);
                    splitx(xA[rt][2], xA[rt][3], ah[rt][1], al[rt][1]);
                }
            }
            __builtin_amdgcn_s_barrier();    // raw barrier: NO implicit drain
        }
    }

    // ---- epilogue: trunc-split stores; Q pre-scaled; V transposed via Vx ----
#pragma unroll
    for (int rt = 0; rt < 2; ++rt) {
        const int tbr = m0 + (w << 5) + (rt << 4);
#pragma unroll
        for (int ct = 0; ct < 6; ++ct) {
            const int gc = y * 96 + (ct << 4);
            if (gc < 128) {
                unsigned short* Dh = (gc < 64) ? Qhi : Khi;
                unsigned short* Dl = (gc < 64) ? Qlo : Klo;
                const float sc = (gc < 64) ? QSCALE : 1.0f;
                const int colb = (gc & 63) + lm;
#pragma unroll
                for (int r = 0; r < 4; ++r) {
                    int row = tbr + (lg << 2) + r;
                    float x = acc[rt][ct][r] * sc;
                    unsigned u = __builtin_bit_cast(unsigned, x);
                    size_t o = (size_t)row * 64 + colb;
                    Dh[o] = (unsigned short)(u >> 16);
                    Dl[o] = bftrunc(x - __builtin_bit_cast(float, u & 0xffff0000u));
                }
            } else {
                // V: 16x16 transpose via wave-local LDS scratch
#pragma unroll
                for (int r = 0; r < 4; ++r)
                    Vx[w * 320 + lm * 20 + (lg << 2) + r] = bftrunc(acc[rt][ct][r]);
                __asm__ volatile("" ::: "memory");
                const int h0 = gc - 128;
                const int bb = tbr >> 11;
                const int tl = (tbr & 2047) + ((l & 3) << 2);
                const int hh2 = h0 + (l >> 2);
                us4 vv = *(const us4*)&Vx[w * 320 + (l >> 2) * 20 + ((l & 3) << 2)];
                *(us4*)&Vthi[(size_t)((bb << 6) + hh2) * 2048 + tl] = vv;
                __asm__ volatile("" ::: "memory");
            }
        }
    }
}

// ---------------- Kernel 2: causal flash attention ----------------
// 512 blocks = (b, 32-row q-tile, heavy-first). 4 waves = 4 key-parities,
// ZERO barriers in the K-loop (K/V frags direct from global, L2-resident).
// S^T layout: lane = q-row -> softmax reduce = 15 local ops + 2 shuffles.
// exp2 domain (Q pre-scaled by 8*log2e). 4-way merge at end.
// (r9 setprio experiment reverted: measured null-to-negative.)
__global__ __launch_bounds__(256, 2) void attn_kernel(
    const unsigned short* __restrict__ Qhi, const unsigned short* __restrict__ Qlo,
    const unsigned short* __restrict__ Khi, const unsigned short* __restrict__ Klo,
    const unsigned short* __restrict__ Vthi,
    float* __restrict__ O)
{
    __shared__ __align__(16) unsigned char smem[33792];
    unsigned short* PS = (unsigned short*)smem;     // [4][32][72] us (loop phase)
    float* FO = (float*)smem;                       // [4][32][64] f32 (merge phase)
    float* FM = (float*)(smem + 32768);             // [4][32]
    float* FL = FM + 128;

    const int t = threadIdx.x;
    const int w = t >> 6, l = t & 63, lm = l & 15, lg = (l >> 4) & 3;
    const int b = blockIdx.x & 7;
    const int qp = 63 - (blockIdx.x >> 3);          // heavy tiles first
    const int nk = (qp >> 1) + 1;                   // 64-key tiles needed
    const int q0 = qp << 5;
    const size_t brow = (size_t)b << 11;

    // Q fragments pinned (B-operand: lane=qrow, k=lg*8+j)
    us8 qh[2][2], ql[2][2];
#pragma unroll
    for (int nt = 0; nt < 2; ++nt)
#pragma unroll
        for (int kc = 0; kc < 2; ++kc) {
            size_t off = (brow + q0 + (nt << 4) + lm) * 64 + (kc << 5) + (lg << 3);
            qh[nt][kc] = *(const us8*)&Qhi[off];
            ql[nt][kc] = *(const us8*)&Qlo[off];
        }

    f32x4 o_acc[2][4];
#pragma unroll
    for (int nt = 0; nt < 2; ++nt)
#pragma unroll
        for (int ct = 0; ct < 4; ++ct) o_acc[nt][ct] = (f32x4){0.f, 0.f, 0.f, 0.f};
    float m_r[2] = {NEG_INF, NEG_INF}, l_r[2] = {0.f, 0.f};
    unsigned short* ps = PS + w * 2304;             // wave-local 32x72

    for (int j = w; j < nk; j += 4) {
        const int kk0 = j << 6;
        us8 kh[4][2], klo[4][2], vh[4][2];
#pragma unroll
        for (int mt = 0; mt < 4; ++mt)
#pragma unroll
            for (int kc = 0; kc < 2; ++kc) {
                size_t off = (brow + kk0 + (mt << 4) + lm) * 64 + (kc << 5) + (lg << 3);
                kh[mt][kc] = *(const us8*)&Khi[off];
                klo[mt][kc] = *(const us8*)&Klo[off];
            }
#pragma unroll
        for (int ct = 0; ct < 4; ++ct)
#pragma unroll
            for (int kc = 0; kc < 2; ++kc) {
                size_t off = ((size_t)(b << 6) + (ct << 4) + lm) * 2048
                           + kk0 + (kc << 5) + (lg << 3);
                vh[ct][kc] = *(const us8*)&Vthi[off];
            }
        // S^T = K Q^T (split-bf16)
        f32x4 s[4][2];
#pragma unroll
        for (int mt = 0; mt < 4; ++mt)
#pragma unroll
            for (int nt = 0; nt < 2; ++nt) s[mt][nt] = (f32x4){0.f, 0.f, 0.f, 0.f};
#pragma unroll
        for (int kc = 0; kc < 2; ++kc)
#pragma unroll
            for (int mt = 0; mt < 4; ++mt)
#pragma unroll
                for (int nt = 0; nt < 2; ++nt) {
                    s[mt][nt] = mfma16(kh[mt][kc], qh[nt][kc], s[mt][nt]);
                    s[mt][nt] = mfma16(klo[mt][kc], qh[nt][kc], s[mt][nt]);
                    s[mt][nt] = mfma16(kh[mt][kc], ql[nt][kc], s[mt][nt]);
                }
        // online softmax (exp2 domain), lane owns row q0+nt*16+lm, 16 keys
        float alz[2];
#pragma unroll
        for (int nt = 0; nt < 2; ++nt) {
            const int qr = q0 + (nt << 4) + lm;
            float sv[16];
            if ((kk0 + 63) <= (q0 + (nt << 4))) {
#pragma unroll
                for (int mt = 0; mt < 4; ++mt)
#pragma unroll
                    for (int r = 0; r < 4; ++r) sv[(mt << 2) + r] = s[mt][nt][r];
            } else {
#pragma unroll
                for (int mt = 0; mt < 4; ++mt)
#pragma unroll
                    for (int r = 0; r < 4; ++r) {
                        const int key = kk0 + (mt << 4) + (lg << 2) + r;
                        sv[(mt << 2) + r] = (key <= qr) ? s[mt][nt][r] : NEG_INF;
                    }
            }
            float t8[8];
#pragma unroll
            for (int i = 0; i < 8; ++i) t8[i] = fmaxf(sv[i], sv[i + 8]);
#pragma unroll
            for (int i = 0; i < 4; ++i) t8[i] = fmaxf(t8[i], t8[i + 4]);
            float mx = fmaxf(fmaxf(t8[0], t8[1]), fmaxf(t8[2], t8[3]));
            mx = fmaxf(mx, __shfl_xor(mx, 16));
            mx = fmaxf(mx, __shfl_xor(mx, 32));
            const float mn = fmaxf(m_r[nt], mx);
            alz[nt] = fexp2(m_r[nt] - mn);
            m_r[nt] = mn;
            float p[16];
#pragma unroll
            for (int i = 0; i < 16; ++i) p[i] = fexp2(sv[i] - mn);
#pragma unroll
            for (int mt = 0; mt < 4; ++mt) {
                us4 pk;
#pragma unroll
                for (int r = 0; r < 4; ++r) pk[r] = bftrunc(p[(mt << 2) + r]);
                *(us4*)&ps[((nt << 4) + lm) * 72 + (mt << 4) + (lg << 2)] = pk;
            }
            float s8[8];
#pragma unroll
            for (int i = 0; i < 8; ++i) s8[i] = p[i] + p[i + 8];
#pragma unroll
            for (int i = 0; i < 4; ++i) s8[i] = s8[i] + s8[i + 4];
            float rs = (s8[0] + s8[1]) + (s8[2] + s8[3]);
            rs += __shfl_xor(rs, 16);
            rs += __shfl_xor(rs, 32);
            l_r[nt] = l_r[nt] * alz[nt] + rs;
        }
        __asm__ volatile("" ::: "memory");   // P write -> read, same wave
        // rescale O (alz lives at lane=row; fetch via shuffle)
#pragma unroll
        for (int nt = 0; nt < 2; ++nt)
#pragma unroll
            for (int r = 0; r < 4; ++r) {
                const float av = __shfl(alz[nt], (lg << 2) + r);
#pragma unroll
                for (int ct = 0; ct < 4; ++ct) o_acc[nt][ct][r] *= av;
            }
        // O += P V
#pragma unroll
        for (int nt = 0; nt < 2; ++nt)
#pragma unroll
            for (int kc = 0; kc < 2; ++kc) {
                us8 pa = *(const us8*)&ps[((nt << 4) + lm) * 72 + (kc << 5) + (lg << 3)];
#pragma unroll
                for (int ct = 0; ct < 4; ++ct)
                    o_acc[nt][ct] = mfma16(pa, vh[ct][kc], o_acc[nt][ct]);
            }
    }

    // ---- 4-way key-parity merge ----
    __syncthreads();                         // all PS use done before FO alias
#pragma unroll
    for (int nt = 0; nt < 2; ++nt)
#pragma unroll
        for (int ct = 0; ct < 4; ++ct)
#pragma unroll
            for (int r = 0; r < 4; ++r)
                FO[(w << 11) + (((nt << 4) + (lg << 2) + r) << 6) + (ct << 4) + lm]
                    = o_acc[nt][ct][r];
    if (l < 16) {
        FM[(w << 5) + lm] = m_r[0]; FM[(w << 5) + 16 + lm] = m_r[1];
        FL[(w << 5) + lm] = l_r[0]; FL[(w << 5) + 16 + lm] = l_r[1];
    }
    __syncthreads();
    const int jr = t >> 3;                   // row 0..31
    const int cg = (t & 7) << 3;             // col base
    float m0v = FM[jr], m1v = FM[32 + jr], m2v = FM[64 + jr], m3v = FM[96 + jr];
    float mm = fmaxf(fmaxf(m0v, m1v), fmaxf(m2v, m3v));
    float a0 = fexp2(m0v - mm), a1 = fexp2(m1v - mm);
    float a2 = fexp2(m2v - mm), a3 = fexp2(m3v - mm);
    float L = a0 * FL[jr] + a1 * FL[32 + jr] + a2 * FL[64 + jr] + a3 * FL[96 + jr];
    float inv = 1.0f / L;
    float ov[8];
#pragma unroll
    for (int c = 0; c < 8; ++c)
        ov[c] = a0 * FO[(jr << 6) + cg + c] + a1 * FO[2048 + (jr << 6) + cg + c]
              + a2 * FO[4096 + (jr << 6) + cg + c] + a3 * FO[6144 + (jr << 6) + cg + c];
    float4 o1 = {ov[0] * inv, ov[1] * inv, ov[2] * inv, ov[3] * inv};
    float4 o2 = {ov[4] * inv, ov[5] * inv, ov[6] * inv, ov[7] * inv};
    float* op = O + (brow + q0 + jr) * 64 + cg;
    *(float4*)op = o1;
    *(float4*)(op + 4) = o2;
}

extern "C" void kernel_launch(void* const* d_in, const int* in_sizes, int n_in,
                              void* d_out, int out_size, void* d_ws, size_t ws_size,
                              hipStream_t stream) {
    const float* X  = (const float*)d_in[0];
    const float* Wq = (const float*)d_in[1];
    const float* Wk = (const float*)d_in[2];
    const float* Wv = (const float*)d_in[3];
    unsigned short* ws = (unsigned short*)d_ws;
    const size_t SZ = (size_t)16384 * 64;
    unsigned short* Qhi  = ws;
    unsigned short* Qlo  = ws + SZ;
    unsigned short* Khi  = ws + 2 * SZ;
    unsigned short* Klo  = ws + 3 * SZ;
    unsigned short* Vthi = ws + 4 * SZ;
    unsigned short* Wthi = ws + 5 * SZ;
    unsigned short* Wtlo = Wthi + 192 * 1024;

    wprep_kernel<<<48, 256, 0, stream>>>(Wq, Wk, Wv, Wthi, Wtlo);
    qkv_kernel<<<dim3(256, 2), 128, 0, stream>>>(X, Wthi, Wtlo,
                                                 Qhi, Qlo, Khi, Klo, Vthi);
    attn_kernel<<<512, 256, 0, stream>>>(Qhi, Qlo, Khi, Klo, Vthi, (float*)d_out);
}